// Round 4
// baseline (248.785 us; speedup 1.0000x reference)
//
#include <hip/hip_runtime.h>

#define T_DIM 1600
#define N_DIM 32
#define C_DIM 512
#define S_DIM 200
#define RCP_LN2 1.44269504088896340736f
#define LN2F 0.69314718055994530942f
#define ESENT (-(1 << 28))

static __device__ __forceinline__ float fast_exp2(float x) {
#if __has_builtin(__builtin_amdgcn_exp2f)
    return __builtin_amdgcn_exp2f(x);
#else
    return exp2f(x);
#endif
}

static __device__ __forceinline__ float fast_log2(float x) {
#if __has_builtin(__builtin_amdgcn_logf)
    return __builtin_amdgcn_logf(x);
#else
    return log2f(x);
#endif
}

// ---- DPP cross-lane helpers (VALU pipe) ----
static __device__ __forceinline__ float dpp_shr1_f(float x) {
    return __int_as_float(__builtin_amdgcn_update_dpp(
        0, __float_as_int(x), 0x138, 0xf, 0xf, false));  // lane0 -> 0.0f
}
static __device__ __forceinline__ int dpp_shr1_i(int x, int old0) {
    return __builtin_amdgcn_update_dpp(old0, x, 0x138, 0xf, 0xf, false);
}
static __device__ __forceinline__ int dpp_prefix_max_i(int x) {
    int t;
    t = __builtin_amdgcn_update_dpp(x, x, 0x111, 0xf, 0xf, false); x = (t > x) ? t : x;
    t = __builtin_amdgcn_update_dpp(x, x, 0x112, 0xf, 0xf, false); x = (t > x) ? t : x;
    t = __builtin_amdgcn_update_dpp(x, x, 0x114, 0xf, 0xf, false); x = (t > x) ? t : x;
    t = __builtin_amdgcn_update_dpp(x, x, 0x118, 0xf, 0xf, false); x = (t > x) ? t : x;
    t = __builtin_amdgcn_update_dpp(x, x, 0x142, 0xf, 0xf, false); x = (t > x) ? t : x;
    t = __builtin_amdgcn_update_dpp(x, x, 0x143, 0xf, 0xf, false); x = (t > x) ? t : x;
    return x;
}

// async HBM -> LDS, 16 B/lane; lds base wave-uniform (HW adds lane*16)
static __device__ __forceinline__ void gl_lds16(const float* g, float* l) {
    __builtin_amdgcn_global_load_lds(
        (const __attribute__((address_space(1))) unsigned int*)g,
        (__attribute__((address_space(3))) unsigned int*)l, 16, 0, 0);
}

#define VMWAIT16() __builtin_amdgcn_s_waitcnt(0x4F70)  // vmcnt(16), lgkm free

// ws layout: [0..31] int counters (zeroed per launch); data at ws+64:
//   per n (1152 floats): afin[512], bfin[512], escF[64 ints], escB[64 ints]
__global__ __launch_bounds__(64) void ctc_dp(
    const float* __restrict__ lp, const int* __restrict__ tgts,
    const int* __restrict__ input_lens, const int* __restrict__ target_lens,
    float* __restrict__ out, float* __restrict__ ws)
{
    __shared__ float rows[3][8][C_DIM];   // 48 KB staging ring (one role/block)

    const int blk = blockIdx.x;
    const int n = blk >> 1;
    const int role = blk & 1;          // 0 = forward wave, 1 = backward wave
    const int lane = threadIdx.x & 63;
    const int* tgt = tgts + n * S_DIM;

    int len = input_lens[n];
    if (len > T_DIM) len = T_DIM;
    const int lenc = (len < 1) ? 1 : len;
    const int tl = target_lens[n];
    const int mid = (lenc + 1) >> 1;   // forward steps t=0..mid-1
    const int nsb = lenc - mid;        // backward steps t=lenc-1..mid

    float* afin_g = ws + 64 + (size_t)n * 1152;
    float* bfin_g = afin_g + 512;
    int* escF_g = (int*)(afin_g + 1024);
    int* escB_g = escF_g + 64;
    int* counter = (int*)ws + n;

#define TMAP_F(ti_) ((ti_) > mid - 1 ? mid - 1 : (ti_))
#define TMAP_B(ti_) (lenc - 1 - (ti_) < 0 ? 0 : lenc - 1 - (ti_))

#define ISSUE(B_, c_, TMAP_) do {                                             \
        int tb_ = (c_) * 8;                                                   \
        _Pragma("unroll")                                                     \
        for (int r_ = 0; r_ < 8; ++r_) {                                      \
            int ti_ = tb_ + r_;                                               \
            int t_ = TMAP_(ti_);                                              \
            const float* g_ = lp + ((size_t)t_ * N_DIM + n) * C_DIM + lane*4; \
            gl_lds16(g_,       &rows[(B_)][r_][0]);                           \
            gl_lds16(g_ + 256, &rows[(B_)][r_][256]);                         \
        }                                                                     \
    } while (0)

    // RAW gather only: 40 ds_read with NO consumer this phase -> their 120cy
    // latency is hidden behind the whole next compute phase. exp2 conversion
    // happens at consume time (COMPUTE), one phase later.
#define GATHER_RAW(B_, LAB_, qb_, q1_, q3_, q5_, q7_) do {                    \
        _Pragma("unroll")                                                     \
        for (int r_ = 0; r_ < 8; ++r_) {                                      \
            qb_[r_] = rows[(B_)][r_][0];                                      \
            q1_[r_] = rows[(B_)][r_][LAB_[0]];                                \
            q3_[r_] = rows[(B_)][r_][LAB_[1]];                                \
            q5_[r_] = rows[(B_)][r_][LAB_[2]];                                \
            q7_[r_] = rows[(B_)][r_][LAB_[3]];                                \
        }                                                                     \
    } while (0)

#define BOUNDARY() do {                                                       \
        float lm_ = fmaxf(fmaxf(fmaxf(a0, a1), fmaxf(a2, a3)),                \
                          fmaxf(fmaxf(a4, a5), fmaxf(a6, a7)));               \
        bool nz_ = (lm_ > 0.0f);                                              \
        int kl_ = (int)((__float_as_uint(lm_) >> 23) & 0xffu) - 127;          \
        int prop_ = nz_ ? (E + kl_) : ESENT;                                  \
        int g_ = dpp_prefix_max_i(prop_ + 32 * lane);                         \
        int Efin_ = g_ - 32 * lane;                                           \
        if (nz_) {                                                            \
            int sh_ = E - Efin_;                                              \
            int h1_ = sh_ / 2, h2_ = sh_ - h1_;                               \
            float f_ = fast_exp2((float)h1_), gg_ = fast_exp2((float)h2_);    \
            float fg_ = f_ * gg_;                                             \
            a0 *= fg_; a1 *= fg_; a2 *= fg_; a3 *= fg_;                       \
            a4 *= fg_; a5 *= fg_; a6 *= fg_; a7 *= fg_;                       \
        }                                                                     \
        int Eprev_ = dpp_shr1_i(Efin_, ESENT);                                \
        E = Efin_;                                                            \
        if (lane == 0) {                                                      \
            scale_d = 0.0f;                                                   \
        } else {                                                              \
            int d_ = Eprev_ - Efin_;      /* <= 32 by construction */         \
            scale_d = (d_ < -126) ? 0.0f : fast_exp2((float)d_);              \
        }                                                                     \
    } while (0)

    // DP steps; converts raw logprobs at consume time (reads were issued a
    // full phase earlier -> no LDS-latency stall; exp2 overlaps row interleave)
#define COMPUTE_F(c8_, FIRST_, qb_, q1_, q3_, q5_, q7_) do {                  \
        _Pragma("unroll")                                                     \
        for (int r_ = 0; r_ < 8; ++r_) {                                      \
            int t_ = (c8_) + r_;                                              \
            if (t_ >= mid) break;                                             \
            float pb_ = fast_exp2(qb_[r_] * RCP_LN2);                         \
            float p1_ = fast_exp2(q1_[r_] * RCP_LN2);                         \
            float p3_ = fast_exp2(q3_[r_] * RCP_LN2);                         \
            float p5_ = fast_exp2(q5_[r_] * RCP_LN2);                         \
            float p7_ = fast_exp2(q7_[r_] * RCP_LN2);                         \
            if ((FIRST_) && r_ == 0) {                                        \
                if (lane == 0) {                                              \
                    a0 = pb_;                                                 \
                    a1 = (tl >= 1) ? p1_ : 0.0f;                              \
                }                                                             \
            } else {                                                          \
                float P_ = dpp_shr1_f(a7) * scale_d;                          \
                float n0_ = (a0 + P_) * pb_;                                  \
                float n1_ = fmaf(sk[0], P_,  a1 + a0) * p1_;                  \
                float n2_ = (a2 + a1) * pb_;                                  \
                float n3_ = fmaf(sk[1], a1, a3 + a2) * p3_;                   \
                float n4_ = (a4 + a3) * pb_;                                  \
                float n5_ = fmaf(sk[2], a3, a5 + a4) * p5_;                   \
                float n6_ = (a6 + a5) * pb_;                                  \
                float n7_ = fmaf(sk[3], a5, a7 + a6) * p7_;                   \
                a0 = n0_; a1 = n1_; a2 = n2_; a3 = n3_;                       \
                a4 = n4_; a5 = n5_; a6 = n6_; a7 = n7_;                       \
            }                                                                 \
        }                                                                     \
    } while (0)

#define COMPUTE_B(c8_, qb_, q1_, q3_, q5_, q7_) do {                          \
        _Pragma("unroll")                                                     \
        for (int r_ = 0; r_ < 8; ++r_) {                                      \
            int ti_ = (c8_) + r_;                                             \
            if (ti_ >= nsb) break;                                            \
            float pb_ = fast_exp2(qb_[r_] * RCP_LN2);                         \
            float p1_ = fast_exp2(q1_[r_] * RCP_LN2);                         \
            float p3_ = fast_exp2(q3_[r_] * RCP_LN2);                         \
            float p5_ = fast_exp2(q5_[r_] * RCP_LN2);                         \
            float p7_ = fast_exp2(q7_[r_] * RCP_LN2);                         \
            float c0_ = pb_ * a0, c1_ = p1_ * a1;                             \
            float c2_ = pb_ * a2, c3_ = p3_ * a3;                             \
            float c4_ = pb_ * a4, c5_ = p5_ * a5;                             \
            float c6_ = pb_ * a6, c7_ = p7_ * a7;                             \
            float P_ = dpp_shr1_f(c7_) * scale_d;                             \
            a0 = c0_ + P_;                                                    \
            a1 = fmaf(aH[0], P_,  c1_ + c0_);                                 \
            a2 = c2_ + c1_;                                                   \
            a3 = fmaf(aH[1], c1_, c3_ + c2_);                                 \
            a4 = c4_ + c3_;                                                   \
            a5 = fmaf(aH[2], c3_, c5_ + c4_);                                 \
            a6 = c6_ + c5_;                                                   \
            a7 = fmaf(aH[3], c5_, c7_ + c6_);                                 \
        }                                                                     \
    } while (0)

#define PHASE_F(k_, GB_, GS_, CS_, IB_, F_) do {                              \
        VMWAIT16();                                                           \
        GATHER_RAW(GB_, labidx, qb##GS_, q1##GS_, q3##GS_, q5##GS_, q7##GS_); \
        COMPUTE_F((k_) * 8, F_, qb##CS_, q1##CS_, q3##CS_, q5##CS_, q7##CS_); \
        BOUNDARY();                                                           \
        ISSUE(IB_, (k_) + 3, TMAP_F);                                         \
    } while (0)

#define PHASE_B(k_, GB_, GS_, CS_, IB_) do {                                  \
        VMWAIT16();                                                           \
        GATHER_RAW(GB_, labH, qb##GS_, q1##GS_, q3##GS_, q5##GS_, q7##GS_);   \
        COMPUTE_B((k_) * 8, qb##CS_, q1##CS_, q3##CS_, q5##CS_, q7##CS_);     \
        BOUNDARY();                                                           \
        ISSUE(IB_, (k_) + 3, TMAP_B);                                         \
    } while (0)

    if (role == 0) {
        // =============== forward wave: alpha 0..mid-1 ===============
        int labidx[4];
        float sk[4];
#pragma unroll
        for (int jj = 0; jj < 4; ++jj) {
            int s = lane * 8 + 2 * jj + 1;
            int i = (s - 1) >> 1;
            int lab = 0;
            float al = 0.0f;
            if (i < S_DIM) {
                lab = tgt[i];
                if (s >= 3 && i >= 1) al = (tgt[i] != tgt[i - 1]) ? 1.0f : 0.0f;
            }
            if (lab < 0 || lab >= C_DIM) lab = 0;
            labidx[jj] = lab;
            sk[jj] = al;
        }

        float a0 = 0.0f, a1 = 0.0f, a2 = 0.0f, a3 = 0.0f;
        float a4 = 0.0f, a5 = 0.0f, a6 = 0.0f, a7 = 0.0f;
        int E = 0;
        float scale_d = (lane == 0) ? 0.0f : 1.0f;
        float qbA[8], q1A[8], q3A[8], q5A[8], q7A[8];
        float qbB[8], q1B[8], q3B[8], q5B[8], q7B[8];

        ISSUE(0, 0, TMAP_F);
        ISSUE(1, 1, TMAP_F);
        VMWAIT16();
        GATHER_RAW(0, labidx, qbA, q1A, q3A, q5A, q7A);
        ISSUE(2, 2, TMAP_F);

        const int ncf = (mid + 7) >> 3;
        const int kmaxf = ((ncf + 5) / 6) * 6;
        for (int k6 = 0; k6 < kmaxf; k6 += 6) {
            bool f0 = (k6 == 0);
            PHASE_F(k6 + 0, 1, B, A, 0, f0);
            PHASE_F(k6 + 1, 2, A, B, 1, false);
            PHASE_F(k6 + 2, 0, B, A, 2, false);
            PHASE_F(k6 + 3, 1, A, B, 0, false);
            PHASE_F(k6 + 4, 2, B, A, 1, false);
            PHASE_F(k6 + 5, 0, A, B, 2, false);
        }

        float4 lo = make_float4(a0, a1, a2, a3);
        float4 hi = make_float4(a4, a5, a6, a7);
        reinterpret_cast<float4*>(afin_g)[lane * 2] = lo;
        reinterpret_cast<float4*>(afin_g)[lane * 2 + 1] = hi;
        escF_g[lane] = E;
    } else {
        // =============== backward wave: beta lenc-1..mid ===============
        // hat space: s_hat = 510 - s; even hat = blank (parity preserved)
        int labH[4];
        float aH[4];
#pragma unroll
        for (int jj = 0; jj < 4; ++jj) {
            int shat = lane * 8 + 2 * jj + 1;
            int s = 510 - shat;
            int lab = 0;
            float al = 0.0f;
            if (s >= 1 && s <= 399) {
                lab = tgt[(s - 1) >> 1];
                if (s + 2 <= 400) al = (tgt[(s + 1) >> 1] != tgt[(s - 1) >> 1]) ? 1.0f : 0.0f;
            }
            if (lab < 0 || lab >= C_DIM) lab = 0;
            labH[jj] = lab;
            aH[jj] = al;
        }

        float a0, a1, a2, a3, a4, a5, a6, a7;
#define BINIT(aj_, j_) do {                                                   \
            int s_ = 510 - (lane * 8 + (j_));                                 \
            aj_ = (s_ == 2 * tl || (tl > 0 && s_ == 2 * tl - 1)) ? 1.0f : 0.0f; \
        } while (0)
        BINIT(a0, 0); BINIT(a1, 1); BINIT(a2, 2); BINIT(a3, 3);
        BINIT(a4, 4); BINIT(a5, 5); BINIT(a6, 6); BINIT(a7, 7);
#undef BINIT
        int E = 0;
        float scale_d = (lane == 0) ? 0.0f : 1.0f;
        float qbA[8], q1A[8], q3A[8], q5A[8], q7A[8];
        float qbB[8], q1B[8], q3B[8], q5B[8], q7B[8];

        ISSUE(0, 0, TMAP_B);
        ISSUE(1, 1, TMAP_B);
        VMWAIT16();
        GATHER_RAW(0, labH, qbA, q1A, q3A, q5A, q7A);
        ISSUE(2, 2, TMAP_B);

        const int ncb = (nsb + 7) >> 3;
        const int kmaxb = ((ncb + 5) / 6) * 6;
        for (int k6 = 0; k6 < kmaxb; k6 += 6) {
            PHASE_B(k6 + 0, 1, B, A, 0);
            PHASE_B(k6 + 1, 2, A, B, 1);
            PHASE_B(k6 + 2, 0, B, A, 2);
            PHASE_B(k6 + 3, 1, A, B, 0);
            PHASE_B(k6 + 4, 2, B, A, 1);
            PHASE_B(k6 + 5, 0, A, B, 2);
        }

        float4 lo = make_float4(a0, a1, a2, a3);
        float4 hi = make_float4(a4, a5, a6, a7);
        reinterpret_cast<float4*>(bfin_g)[lane * 2] = lo;
        reinterpret_cast<float4*>(bfin_g)[lane * 2 + 1] = hi;
        escB_g[lane] = E;
    }

    // -------- handshake: second finisher for this n does the combine --------
    __threadfence();                      // release own half (device scope)
    int prev = 0;
    if (lane == 0)
        prev = __hip_atomic_fetch_add(counter, 1, __ATOMIC_ACQ_REL,
                                      __HIP_MEMORY_SCOPE_AGENT);
    prev = __shfl(prev, 0);
    if (prev != 1) return;                // first finisher exits

    __threadfence();                      // acquire other half (inv caches)

    // total = sum_s alpha_{mid-1}[s] * beta_{mid-1}[s], log2 domain
    {
        const int l = lane;
        const int Ef = escF_g[l];
        float m8 = -1e30f, s8 = 0.0f;
#pragma unroll
        for (int j = 0; j < 8; ++j) {
            int s = 8 * l + j;
            float x = -1e30f;
            if (s <= 400) {
                float af = afin_g[s];
                int shat = 510 - s;
                float bf = bfin_g[shat];
                if (af > 0.0f && bf > 0.0f)
                    x = fast_log2(af) + fast_log2(bf) + (float)(Ef + escB_g[shat >> 3]);
            }
            float m2 = fmaxf(m8, x);
            s8 = s8 * fast_exp2(m8 - m2) + fast_exp2(x - m2);
            m8 = m2;
        }
        float M = m8, V = s8;
#pragma unroll
        for (int off = 1; off < 64; off <<= 1) {
            float Mo = __shfl_xor(M, off);
            float Vo = __shfl_xor(V, off);
            float Mn = fmaxf(M, Mo);
            V = V * fast_exp2(M - Mn) + Vo * fast_exp2(Mo - Mn);
            M = Mn;
        }
        if (l == 0) {
            float X = M + fast_log2(V);
            float per_ex = -LN2F * X;
            if (!(per_ex < 1e29f)) per_ex = 0.0f;  // zero_infinity (NaN/inf safe)
            float tlf = (float)tl;
            if (tlf < 1.0f) tlf = 1.0f;
            // fused mean: one device-scope atomic per example (32 total)
            atomicAdd(out, per_ex / sqrtf(tlf) * (1.0f / N_DIM));
        }
    }
#undef ISSUE
#undef GATHER_RAW
#undef BOUNDARY
#undef COMPUTE_F
#undef COMPUTE_B
#undef PHASE_F
#undef PHASE_B
#undef TMAP_F
#undef TMAP_B
}

extern "C" void kernel_launch(void* const* d_in, const int* in_sizes, int n_in,
                              void* d_out, int out_size, void* d_ws, size_t ws_size,
                              hipStream_t stream) {
    (void)in_sizes; (void)n_in; (void)ws_size;
    const float* lp   = (const float*)d_in[0];
    const int* tgts   = (const int*)d_in[1];
    const int* ilens  = (const int*)d_in[2];
    const int* tlens  = (const int*)d_in[3];

    // d_out is poisoned (0xAA) before every timed launch -> zero it first.
    hipMemsetAsync(d_out, 0, (size_t)out_size * sizeof(float), stream);
    // zero the 32 per-example handshake counters at the head of the workspace
    hipMemsetAsync(d_ws, 0, N_DIM * sizeof(int), stream);
    ctc_dp<<<2 * N_DIM, 64, 0, stream>>>(lp, tgts, ilens, tlens,
                                         (float*)d_out, (float*)d_ws);
}

// Round 5
// 230.165 us; speedup vs baseline: 1.0809x; 1.0809x over previous
//
#include <hip/hip_runtime.h>

#define T_DIM 1600
#define N_DIM 32
#define C_DIM 512
#define S_DIM 200
#define RCP_LN2 1.44269504088896340736f
#define LN2F 0.69314718055994530942f
#define ESENT (-(1 << 28))

static __device__ __forceinline__ float fast_exp2(float x) {
#if __has_builtin(__builtin_amdgcn_exp2f)
    return __builtin_amdgcn_exp2f(x);
#else
    return exp2f(x);
#endif
}

static __device__ __forceinline__ float fast_log2(float x) {
#if __has_builtin(__builtin_amdgcn_logf)
    return __builtin_amdgcn_logf(x);
#else
    return log2f(x);
#endif
}

// ---- DPP cross-lane helpers (VALU pipe) ----
static __device__ __forceinline__ float dpp_shr1_f(float x) {
    return __int_as_float(__builtin_amdgcn_update_dpp(
        0, __float_as_int(x), 0x138, 0xf, 0xf, false));  // lane0 -> 0.0f
}
static __device__ __forceinline__ int dpp_shr1_i(int x, int old0) {
    return __builtin_amdgcn_update_dpp(old0, x, 0x138, 0xf, 0xf, false);
}
static __device__ __forceinline__ int dpp_prefix_max_i(int x) {
    int t;
    t = __builtin_amdgcn_update_dpp(x, x, 0x111, 0xf, 0xf, false); x = (t > x) ? t : x;
    t = __builtin_amdgcn_update_dpp(x, x, 0x112, 0xf, 0xf, false); x = (t > x) ? t : x;
    t = __builtin_amdgcn_update_dpp(x, x, 0x114, 0xf, 0xf, false); x = (t > x) ? t : x;
    t = __builtin_amdgcn_update_dpp(x, x, 0x118, 0xf, 0xf, false); x = (t > x) ? t : x;
    t = __builtin_amdgcn_update_dpp(x, x, 0x142, 0xf, 0xf, false); x = (t > x) ? t : x;
    t = __builtin_amdgcn_update_dpp(x, x, 0x143, 0xf, 0xf, false); x = (t > x) ? t : x;
    return x;
}

// async HBM -> LDS, 16 B/lane; lds base wave-uniform (HW adds lane*16)
static __device__ __forceinline__ void gl_lds16(const float* g, float* l) {
    __builtin_amdgcn_global_load_lds(
        (const __attribute__((address_space(1))) unsigned int*)g,
        (__attribute__((address_space(3))) unsigned int*)l, 16, 0, 0);
}

#define VMWAIT8()  __builtin_amdgcn_s_waitcnt(0x0F78)  // vmcnt(8),  lgkm/exp free
#define VMDRAIN()  __builtin_amdgcn_s_waitcnt(0x0F70)  // vmcnt(0),  lgkm/exp free
// Phase barrier: drain LDS (lgkmcnt(0)) but leave global_load_lds prefetches
// in flight across the barrier (NO vmcnt drain -- __syncthreads would add one).
#define PHASE_SYNC() do {                                                     \
        __builtin_amdgcn_sched_barrier(0);                                    \
        __builtin_amdgcn_s_waitcnt(0xC07F);   /* lgkmcnt(0) only */           \
        __builtin_amdgcn_s_barrier();                                         \
        __builtin_amdgcn_sched_barrier(0);                                    \
    } while (0)

// ws layout: [0..31] int counters (zeroed per launch); data at ws+64:
//   per n (1152 floats): afin[512], bfin[512], escF[64 ints], escB[64 ints]
__global__ __launch_bounds__(192) void ctc_dp(
    const float* __restrict__ lp, const int* __restrict__ tgts,
    const int* __restrict__ input_lens, const int* __restrict__ target_lens,
    float* __restrict__ out, float* __restrict__ ws)
{
    __shared__ float rows[3][8][C_DIM];   // 48 KB producer staging ring
    __shared__ float slab[2][5][8][64];   // 20 KB converted probs, dbuf, lane-contig

    const int blk = blockIdx.x;
    const int n = blk >> 1;
    const int role = blk & 1;          // 0 = forward block, 1 = backward block
    const int tid = threadIdx.x;
    const int wid = tid >> 6;          // 0 = consumer wave, 1/2 = producer waves
    const int lane = tid & 63;
    const int* tgt = tgts + n * S_DIM;

    int len = input_lens[n];
    if (len > T_DIM) len = T_DIM;
    const int lenc = (len < 1) ? 1 : len;
    const int tl = target_lens[n];
    const int mid = (lenc + 1) >> 1;   // forward steps t=0..mid-1
    const int nsb = lenc - mid;        // backward steps t=lenc-1..mid
    const int nsteps = (role == 0) ? mid : nsb;
    const int nc = (nsteps + 7) >> 3;  // chunks of 8 rows

    float* afin_g = ws + 64 + (size_t)n * 1152;
    float* bfin_g = afin_g + 512;
    int* escF_g = (int*)(afin_g + 1024);
    int* escB_g = escF_g + 64;
    int* counter = (int*)ws + n;

    // per-lane labels (producers gather; consumer uses skip coefs)
    int lab[4];
    float skh[4];
    if (role == 0) {
#pragma unroll
        for (int jj = 0; jj < 4; ++jj) {
            int s = lane * 8 + 2 * jj + 1;
            int i = (s - 1) >> 1;
            int lb = 0;
            float al = 0.0f;
            if (i < S_DIM) {
                lb = tgt[i];
                if (s >= 3 && i >= 1) al = (tgt[i] != tgt[i - 1]) ? 1.0f : 0.0f;
            }
            if (lb < 0 || lb >= C_DIM) lb = 0;
            lab[jj] = lb;
            skh[jj] = al;
        }
    } else {
        // hat space: s_hat = 510 - s; even hat = blank (parity preserved)
#pragma unroll
        for (int jj = 0; jj < 4; ++jj) {
            int shat = lane * 8 + 2 * jj + 1;
            int s = 510 - shat;
            int lb = 0;
            float al = 0.0f;
            if (s >= 1 && s <= 399) {
                lb = tgt[(s - 1) >> 1];
                if (s + 2 <= 400) al = (tgt[(s + 1) >> 1] != tgt[(s - 1) >> 1]) ? 1.0f : 0.0f;
            }
            if (lb < 0 || lb >= C_DIM) lb = 0;
            lab[jj] = lb;
            skh[jj] = al;
        }
    }

    const int r0 = (wid == 1) ? 0 : 4;   // producer wave's 4-row base

    auto tmap = [&](int ti) -> int {
        if (role == 0) return ti > mid - 1 ? mid - 1 : ti;
        int t = lenc - 1 - ti;
        return t < 0 ? 0 : t;
    };

    // producer: coalesced stage of this wave's 4 rows of chunk c_ into ring B_
#define STAGE(B_, c_) do {                                                    \
        _Pragma("unroll")                                                     \
        for (int rr_ = 0; rr_ < 4; ++rr_) {                                   \
            int r_ = r0 + rr_;                                                \
            int t_ = tmap((c_) * 8 + r_);                                     \
            const float* g_ = lp + ((size_t)t_ * N_DIM + n) * C_DIM + lane*4; \
            gl_lds16(g_,       &rows[(B_)][r_][0]);                           \
            gl_lds16(g_ + 256, &rows[(B_)][r_][256]);                         \
        }                                                                     \
    } while (0)

    // producer: batched divergent gather (20 reads) -> exp2 -> slab write
#define CONV(B_, S_) do {                                                     \
        float v_[20];                                                         \
        _Pragma("unroll")                                                     \
        for (int rr_ = 0; rr_ < 4; ++rr_) {                                   \
            int r_ = r0 + rr_;                                                \
            v_[rr_ * 5 + 0] = rows[(B_)][r_][0];                              \
            v_[rr_ * 5 + 1] = rows[(B_)][r_][lab[0]];                         \
            v_[rr_ * 5 + 2] = rows[(B_)][r_][lab[1]];                         \
            v_[rr_ * 5 + 3] = rows[(B_)][r_][lab[2]];                         \
            v_[rr_ * 5 + 4] = rows[(B_)][r_][lab[3]];                         \
        }                                                                     \
        __builtin_amdgcn_sched_barrier(0);                                    \
        _Pragma("unroll")                                                     \
        for (int rr_ = 0; rr_ < 4; ++rr_) {                                   \
            int r_ = r0 + rr_;                                                \
            _Pragma("unroll")                                                 \
            for (int j_ = 0; j_ < 5; ++j_)                                    \
                slab[(S_)][j_][r_][lane] =                                    \
                    fast_exp2(v_[rr_ * 5 + j_] * RCP_LN2);                    \
        }                                                                     \
    } while (0)

#define BOUNDARY() do {                                                       \
        float lm_ = fmaxf(fmaxf(fmaxf(a0, a1), fmaxf(a2, a3)),                \
                          fmaxf(fmaxf(a4, a5), fmaxf(a6, a7)));               \
        bool nz_ = (lm_ > 0.0f);                                              \
        int kl_ = (int)((__float_as_uint(lm_) >> 23) & 0xffu) - 127;          \
        int prop_ = nz_ ? (E + kl_) : ESENT;                                  \
        int g_ = dpp_prefix_max_i(prop_ + 32 * lane);                         \
        int Efin_ = g_ - 32 * lane;                                           \
        if (nz_) {                                                            \
            int sh_ = E - Efin_;                                              \
            int h1_ = sh_ / 2, h2_ = sh_ - h1_;                               \
            float f_ = fast_exp2((float)h1_), gg_ = fast_exp2((float)h2_);    \
            float fg_ = f_ * gg_;                                             \
            a0 *= fg_; a1 *= fg_; a2 *= fg_; a3 *= fg_;                       \
            a4 *= fg_; a5 *= fg_; a6 *= fg_; a7 *= fg_;                       \
        }                                                                     \
        int Eprev_ = dpp_shr1_i(Efin_, ESENT);                                \
        E = Efin_;                                                            \
        if (lane == 0) {                                                      \
            scale_d = 0.0f;                                                   \
        } else {                                                              \
            int d_ = Eprev_ - Efin_;      /* <= 32 by construction */         \
            scale_d = (d_ < -126) ? 0.0f : fast_exp2((float)d_);              \
        }                                                                     \
    } while (0)

    // consumer: batched slab reads (conflict-free) then pure-FMA DP
#define CONSUME_F(c8_, S_, FIRST_) do {                                       \
        float q_[40];                                                         \
        _Pragma("unroll")                                                     \
        for (int r_ = 0; r_ < 8; ++r_)                                        \
            _Pragma("unroll")                                                 \
            for (int j_ = 0; j_ < 5; ++j_)                                    \
                q_[r_ * 5 + j_] = slab[(S_)][j_][r_][lane];                   \
        __builtin_amdgcn_sched_barrier(0);                                    \
        _Pragma("unroll")                                                     \
        for (int r_ = 0; r_ < 8; ++r_) {                                      \
            int t_ = (c8_) + r_;                                              \
            if (t_ >= mid) break;                                             \
            float pb_ = q_[r_ * 5 + 0];                                       \
            float p1_ = q_[r_ * 5 + 1];                                       \
            float p3_ = q_[r_ * 5 + 2];                                       \
            float p5_ = q_[r_ * 5 + 3];                                       \
            float p7_ = q_[r_ * 5 + 4];                                       \
            if ((FIRST_) && r_ == 0) {                                        \
                if (lane == 0) {                                              \
                    a0 = pb_;                                                 \
                    a1 = (tl >= 1) ? p1_ : 0.0f;                              \
                }                                                             \
            } else {                                                          \
                float P_ = dpp_shr1_f(a7) * scale_d;                          \
                float n0_ = (a0 + P_) * pb_;                                  \
                float n1_ = fmaf(skh[0], P_,  a1 + a0) * p1_;                 \
                float n2_ = (a2 + a1) * pb_;                                  \
                float n3_ = fmaf(skh[1], a1, a3 + a2) * p3_;                  \
                float n4_ = (a4 + a3) * pb_;                                  \
                float n5_ = fmaf(skh[2], a3, a5 + a4) * p5_;                  \
                float n6_ = (a6 + a5) * pb_;                                  \
                float n7_ = fmaf(skh[3], a5, a7 + a6) * p7_;                  \
                a0 = n0_; a1 = n1_; a2 = n2_; a3 = n3_;                       \
                a4 = n4_; a5 = n5_; a6 = n6_; a7 = n7_;                       \
            }                                                                 \
        }                                                                     \
    } while (0)

#define CONSUME_B(c8_, S_) do {                                               \
        float q_[40];                                                         \
        _Pragma("unroll")                                                     \
        for (int r_ = 0; r_ < 8; ++r_)                                        \
            _Pragma("unroll")                                                 \
            for (int j_ = 0; j_ < 5; ++j_)                                    \
                q_[r_ * 5 + j_] = slab[(S_)][j_][r_][lane];                   \
        __builtin_amdgcn_sched_barrier(0);                                    \
        _Pragma("unroll")                                                     \
        for (int r_ = 0; r_ < 8; ++r_) {                                      \
            int ti_ = (c8_) + r_;                                             \
            if (ti_ >= nsb) break;                                            \
            float pb_ = q_[r_ * 5 + 0];                                       \
            float p1_ = q_[r_ * 5 + 1];                                       \
            float p3_ = q_[r_ * 5 + 2];                                       \
            float p5_ = q_[r_ * 5 + 3];                                       \
            float p7_ = q_[r_ * 5 + 4];                                       \
            float c0_ = pb_ * a0, c1_ = p1_ * a1;                             \
            float c2_ = pb_ * a2, c3_ = p3_ * a3;                             \
            float c4_ = pb_ * a4, c5_ = p5_ * a5;                             \
            float c6_ = pb_ * a6, c7_ = p7_ * a7;                             \
            float P_ = dpp_shr1_f(c7_) * scale_d;                             \
            a0 = c0_ + P_;                                                    \
            a1 = fmaf(skh[0], P_,  c1_ + c0_);                                \
            a2 = c2_ + c1_;                                                   \
            a3 = fmaf(skh[1], c1_, c3_ + c2_);                                \
            a4 = c4_ + c3_;                                                   \
            a5 = fmaf(skh[2], c3_, c5_ + c4_);                                \
            a6 = c6_ + c5_;                                                   \
            a7 = fmaf(skh[3], c5_, c7_ + c6_);                                \
        }                                                                     \
    } while (0)

    // ---------------- producer prologue ----------------
    if (wid >= 1) {
        STAGE(0, 0);
        STAGE(1, 1);
        VMWAIT8();          // chunk 0 rows staged
        CONV(0, 0);         // slab0 = converted chunk 0
        STAGE(2, 2);
    }
    PHASE_SYNC();           // slab0 visible to consumer

    // consumer DP state
    float a0, a1, a2, a3, a4, a5, a6, a7;
    if (role == 0) {
        a0 = a1 = a2 = a3 = a4 = a5 = a6 = a7 = 0.0f;
    } else {
#define BINIT(aj_, j_) do {                                                   \
            int s_ = 510 - (lane * 8 + (j_));                                 \
            aj_ = (s_ == 2 * tl || (tl > 0 && s_ == 2 * tl - 1)) ? 1.0f : 0.0f; \
        } while (0)
        BINIT(a0, 0); BINIT(a1, 1); BINIT(a2, 2); BINIT(a3, 3);
        BINIT(a4, 4); BINIT(a5, 5); BINIT(a6, 6); BINIT(a7, 7);
#undef BINIT
    }
    int E = 0;
    float scale_d = (lane == 0) ? 0.0f : 1.0f;

    // ---------------- main loop: producers 1 chunk ahead ----------------
    int bg = 1, bi = 0, sw = 1, sr = 0;
    for (int k = 0; k < nc; ++k) {
        if (wid >= 1) {
            VMWAIT8();              // chunk k+1 rows staged (issued 2 phases ago)
            CONV(bg, sw);           // slab[sw] = converted chunk k+1
            STAGE(bi, k + 3);       // prefetch chunk k+3
        } else {
            if (role == 0) { CONSUME_F(k * 8, sr, (k == 0)); }
            else           { CONSUME_B(k * 8, sr); }
            BOUNDARY();
        }
        PHASE_SYNC();
        bg = (bg == 2) ? 0 : bg + 1;
        bi = (bi == 2) ? 0 : bi + 1;
        sw ^= 1;
        sr ^= 1;
    }

    if (wid >= 1) {
        VMDRAIN();   // don't exit with gl_lds in flight into freed LDS
        return;
    }

    // ---------------- consumer: finals + handshake + combine ----------------
    {
        float4 lo = make_float4(a0, a1, a2, a3);
        float4 hi = make_float4(a4, a5, a6, a7);
        if (role == 0) {
            reinterpret_cast<float4*>(afin_g)[lane * 2] = lo;
            reinterpret_cast<float4*>(afin_g)[lane * 2 + 1] = hi;
            escF_g[lane] = E;
        } else {
            reinterpret_cast<float4*>(bfin_g)[lane * 2] = lo;
            reinterpret_cast<float4*>(bfin_g)[lane * 2 + 1] = hi;
            escB_g[lane] = E;
        }
    }

    __threadfence();                      // release own half (device scope)
    int prev = 0;
    if (lane == 0)
        prev = __hip_atomic_fetch_add(counter, 1, __ATOMIC_ACQ_REL,
                                      __HIP_MEMORY_SCOPE_AGENT);
    prev = __shfl(prev, 0);
    if (prev != 1) return;                // first finisher exits

    __threadfence();                      // acquire other half

    // total = sum_s alpha_{mid-1}[s] * beta_{mid-1}[s], log2 domain
    {
        const int l = lane;
        const int Ef = escF_g[l];
        float m8 = -1e30f, s8 = 0.0f;
#pragma unroll
        for (int j = 0; j < 8; ++j) {
            int s = 8 * l + j;
            float x = -1e30f;
            if (s <= 400) {
                float af = afin_g[s];
                int shat = 510 - s;
                float bf = bfin_g[shat];
                if (af > 0.0f && bf > 0.0f)
                    x = fast_log2(af) + fast_log2(bf) + (float)(Ef + escB_g[shat >> 3]);
            }
            float m2 = fmaxf(m8, x);
            s8 = s8 * fast_exp2(m8 - m2) + fast_exp2(x - m2);
            m8 = m2;
        }
        float M = m8, V = s8;
#pragma unroll
        for (int off = 1; off < 64; off <<= 1) {
            float Mo = __shfl_xor(M, off);
            float Vo = __shfl_xor(V, off);
            float Mn = fmaxf(M, Mo);
            V = V * fast_exp2(M - Mn) + Vo * fast_exp2(Mo - Mn);
            M = Mn;
        }
        if (l == 0) {
            float X = M + fast_log2(V);
            float per_ex = -LN2F * X;
            if (!(per_ex < 1e29f)) per_ex = 0.0f;  // zero_infinity (NaN/inf safe)
            float tlf = (float)tl;
            if (tlf < 1.0f) tlf = 1.0f;
            atomicAdd(out, per_ex / sqrtf(tlf) * (1.0f / N_DIM));
        }
    }
#undef STAGE
#undef CONV
#undef BOUNDARY
#undef CONSUME_F
#undef CONSUME_B
}

extern "C" void kernel_launch(void* const* d_in, const int* in_sizes, int n_in,
                              void* d_out, int out_size, void* d_ws, size_t ws_size,
                              hipStream_t stream) {
    (void)in_sizes; (void)n_in; (void)ws_size;
    const float* lp   = (const float*)d_in[0];
    const int* tgts   = (const int*)d_in[1];
    const int* ilens  = (const int*)d_in[2];
    const int* tlens  = (const int*)d_in[3];

    // d_out is poisoned (0xAA) before every timed launch -> zero it first.
    hipMemsetAsync(d_out, 0, (size_t)out_size * sizeof(float), stream);
    // zero the 32 per-example handshake counters at the head of the workspace
    hipMemsetAsync(d_ws, 0, N_DIM * sizeof(int), stream);
    ctc_dp<<<2 * N_DIM, 192, 0, stream>>>(lp, tgts, ilens, tlens,
                                          (float*)d_out, (float*)d_ws);
}